// Round 11
// baseline (812.175 us; speedup 1.0000x reference)
//
#include <hip/hip_runtime.h>
#include <math.h>

#define T_LEN 16384
#define H_DIM 1024
#define C_DIM 256
#define BKC 16

// ---------------- ws layout (float offsets) ----------------
// [0, 786432)        wt    : transposed weights (3, H, C)
// [786432, 802816)   alpha : (T)
// [802816, 819200)   fire_t (int)
// [819200, 835584)   wu1
// [835584, 851968)   wu2
// [851968, 851976)   meta: nf (int), finflag (int)
// [851976, 868360)   atr  : acc trace (T)
// conv partial [T][C] lives in d_out[0 .. T*C) — kscat overwrites it last.

// transpose conv_w (C,H,3) -> wt (3,H,C)  [coalesced writes]
__global__ __launch_bounds__(256) void kwt(const float* __restrict__ w,
                                           float* __restrict__ wt) {
  int idx = blockIdx.x * 256 + threadIdx.x;   // = h*256 + c
  int h = idx >> 8;
  int c = idx & 255;
  const float* s = w + ((size_t)c * H_DIM + h) * 3;
  float a0 = s[0], a1 = s[1], a2 = s[2];
  wt[((size_t)0 * H_DIM + h) * C_DIM + c] = a0;
  wt[((size_t)1 * H_DIM + h) * C_DIM + c] = a1;
  wt[((size_t)2 * H_DIM + h) * C_DIM + c] = a2;
}

// conv1d(K=3), 3-tap fused, 8x4 blocking, BM=64 x BN=128, full K.
// DOUBLE-BUFFERED: A/B staging for kt+1 issued BEFORE compute of kt
// (~3000 FMA-cyc between issue and the barrier's vmcnt drain -> latency
// hidden; was issued right before the barrier = ~23% stall). One barrier
// per kt (was 2). FMA order per output unchanged -> alpha bit-identical.
__global__ __launch_bounds__(256) void kconv(
    const float* __restrict__ x, const float* __restrict__ wt,
    float* __restrict__ part)
{
  __shared__ float As[2][BKC][68];      // 2 x 4.35 KB
  __shared__ float Bs[2][3][BKC][128];  // 2 x 24 KB  (total 57.8 KB)
  const int tid  = threadIdx.x;
  const int tile = blockIdx.x >> 1;
  const int ch   = blockIdx.x & 1;
  const int t0   = tile * 64;
  const int c0   = ch * 128;
  const int i = tid >> 5;        // 0..7  row group (rows 8i..8i+7)
  const int j = tid & 31;        // 0..31 col group (cols c0+4j..+3)
  const int wv   = tid >> 6;     // wave 0..3
  const int lane = tid & 63;

  float acc[8][4];
  #pragma unroll
  for (int a0 = 0; a0 < 8; ++a0)
    #pragma unroll
    for (int b0 = 0; b0 < 4; ++b0) acc[a0][b0] = 0.f;

  const int tloc = tid >> 2;                 // 0..63 A-stage row
  const int hg   = tid & 3;                  // h sub-group
  const int tr   = t0 + tloc - 1;            // halo row t0-1
  const bool trok = (tr >= 0 && tr < T_LEN);
  const int tl2  = 64 + (tid >> 2);          // rows 64,65 (tid<8 only)
  const int tr2  = t0 + tl2 - 1;
  const bool tr2ok = (tid < 8) && (tr2 < T_LEN);

  float4 areg0, areg1;

#define A_LOAD(H0)                                                            \
  areg0 = make_float4(0.f, 0.f, 0.f, 0.f); areg1 = areg0;                     \
  if (trok)  areg0 = *(const float4*)(x + (size_t)tr  * H_DIM + (H0) + 4*hg); \
  if (tr2ok) areg1 = *(const float4*)(x + (size_t)tr2 * H_DIM + (H0) + 4*(tid&3));

#define A_WRITE(BUF)                                                          \
  As[BUF][4*hg+0][tloc] = areg0.x; As[BUF][4*hg+1][tloc] = areg0.y;           \
  As[BUF][4*hg+2][tloc] = areg0.z; As[BUF][4*hg+3][tloc] = areg0.w;           \
  if (tid < 8) {                                                              \
    const int hg2 = (tid & 3) * 4;                                            \
    As[BUF][hg2+0][tl2] = areg1.x; As[BUF][hg2+1][tl2] = areg1.y;             \
    As[BUF][hg2+2][tl2] = areg1.z; As[BUF][hg2+3][tl2] = areg1.w;             \
  }

#define B_ISSUE(H0, BUF)                                                      \
  _Pragma("unroll")                                                           \
  for (int it = 0; it < 6; ++it) {                                            \
    const int r  = 6 * wv + it;          /* 0..23 */                          \
    const int dl = r >> 3;               /* tap 0..2 */                       \
    const int kk = (r & 7) * 2;          /* h_local 0,2,..,14 */              \
    const float* src = wt + ((size_t)dl * H_DIM + (H0) + kk + (lane >> 5)) * C_DIM \
                          + c0 + 4 * (lane & 31);                             \
    __builtin_amdgcn_global_load_lds(                                         \
        (const __attribute__((address_space(1))) unsigned int*)src,           \
        (__attribute__((address_space(3))) unsigned int*)&Bs[BUF][dl][kk][0], \
        16, 0, 0);                                                            \
  }

#define COMPUTE8(BUF, KLO)                                                    \
  _Pragma("unroll")                                                           \
  for (int k = (KLO); k < (KLO) + 8; ++k) {                                   \
    float aw[10];                                                             \
    *(float4*)&aw[0] = *(const float4*)&As[BUF][k][8 * i];                    \
    *(float4*)&aw[4] = *(const float4*)&As[BUF][k][8 * i + 4];                \
    *(float2*)&aw[8] = *(const float2*)&As[BUF][k][8 * i + 8];                \
    float bw[3][4];                                                           \
    _Pragma("unroll")                                                         \
    for (int dl = 0; dl < 3; ++dl)                                            \
      *(float4*)&bw[dl][0] = *(const float4*)&Bs[BUF][dl][k][4 * j];          \
    _Pragma("unroll")                                                         \
    for (int ii = 0; ii < 8; ++ii)                                            \
      _Pragma("unroll")                                                       \
      for (int qq = 0; qq < 4; ++qq)                                          \
        acc[ii][qq] = fmaf(aw[ii],     bw[0][qq],                             \
                      fmaf(aw[ii + 1], bw[1][qq],                             \
                      fmaf(aw[ii + 2], bw[2][qq], acc[ii][qq])));             \
  }

  // prologue: stage kt=0 into buffer 0 (one cold-latency barrier, once)
  A_LOAD(0); B_ISSUE(0, 0); A_WRITE(0);
  __syncthreads();

  for (int kt = 0; kt < 64; kt += 2) {
    // ---- even step: compute buf0 (kt), prefetch kt+1 -> buf1 ----
    {
      const int h1 = (kt + 1) * BKC;          // kt+1 <= 63 always here
      A_LOAD(h1); B_ISSUE(h1, 1);
      COMPUTE8(0, 0);
      A_WRITE(1);                              // waits aregs only (vmcnt ordered)
      COMPUTE8(0, 8);
      __syncthreads();   // drains: B(kt+1) issued ~3000cyc ago; As writes ~1500
    }
    // ---- odd step: compute buf1 (kt+1), prefetch kt+2 -> buf0 ----
    {
      const int h2 = (kt + 2) * BKC;
      if (kt + 2 < 64) { A_LOAD(h2); B_ISSUE(h2, 0); }
      COMPUTE8(1, 0);
      if (kt + 2 < 64) { A_WRITE(0); }
      COMPUTE8(1, 8);
      __syncthreads();
    }
  }

  #pragma unroll
  for (int ii = 0; ii < 8; ++ii) {
    const size_t t = t0 + 8 * i + ii;
    *(float4*)&part[t * C_DIM + c0 + 4 * j] =
        make_float4(acc[ii][0], acc[ii][1], acc[ii][2], acc[ii][3]);
  }
#undef A_LOAD
#undef A_WRITE
#undef B_ISSUE
#undef COMPUTE8
}

// bias + LN + ReLU + linear + sigmoid -> alpha[t]; one wave per t-row.
__global__ __launch_bounds__(64) void kadd(
    const float* __restrict__ part, const float* __restrict__ cb,
    const float* __restrict__ lng, const float* __restrict__ lnb,
    const float* __restrict__ lw, const float* __restrict__ lb,
    float* __restrict__ alpha)
{
  const int row = blockIdx.x;
  const int l = threadIdx.x;            // 0..63, cols 4l..4l+3
  const float4 p0 = *(const float4*)&part[(size_t)row * C_DIM + 4 * l];
  const float4 cb4 = *(const float4*)&cb[4 * l];
  float v[4] = {p0.x + cb4.x, p0.y + cb4.y, p0.z + cb4.z, p0.w + cb4.w};
  float s = v[0] + v[1] + v[2] + v[3];
  #pragma unroll
  for (int m = 1; m < 64; m <<= 1) s += __shfl_xor(s, m, 64);
  const float mu = s * (1.0f / 256.0f);
  float ss = 0.f;
  #pragma unroll
  for (int q = 0; q < 4; ++q) { const float d = v[q] - mu; ss += d * d; }
  #pragma unroll
  for (int m = 1; m < 64; m <<= 1) ss += __shfl_xor(ss, m, 64);
  const float rstd = 1.0f / sqrtf(ss * (1.0f / 256.0f) + 1e-5f);
  const float4 g4 = *(const float4*)&lng[4 * l];
  const float4 b4 = *(const float4*)&lnb[4 * l];
  const float4 w4 = *(const float4*)&lw[4 * l];
  const float gg[4] = {g4.x, g4.y, g4.z, g4.w};
  const float bb[4] = {b4.x, b4.y, b4.z, b4.w};
  const float ww[4] = {w4.x, w4.y, w4.z, w4.w};
  float dot = 0.f;
  #pragma unroll
  for (int q = 0; q < 4; ++q) {
    float h = (v[q] - mu) * rstd * gg[q] + bb[q];
    h = fmaxf(h, 0.f);
    dot = fmaf(h, ww[q], dot);
  }
  #pragma unroll
  for (int m = 1; m < 64; m <<= 1) dot += __shfl_xor(dot, m, 64);
  if (l == 0)
    alpha[row] = 1.0f / (1.0f + expf(-(dot + lb[0])));
}

// exact-fp32 serial CIF chain. Ping-pong 32-elem buffers, padded LDS,
// 5-op exact core. Op order matches jax bit-for-bit.
__global__ __launch_bounds__(256) void kscan(const float* __restrict__ alpha,
                                             float* __restrict__ atr)
{
  __shared__ float sa[T_LEN + 64];   // 64-float pad: prefetch runs past end
  const int tid = threadIdx.x;
  #pragma unroll
  for (int b = 0; b < 16; ++b)
    ((float4*)sa)[b * 256 + tid] = ((const float4*)alpha)[b * 256 + tid];
  if (tid < 16)
    ((float4*)sa)[4096 + tid] = make_float4(0.f, 0.f, 0.f, 0.f);
  __syncthreads();
  if (tid != 0) return;

  const float4* sa4 = (const float4*)sa;
  float acc = 0.f;
  float4 A[8], B[8];
  #pragma unroll
  for (int b = 0; b < 8; ++b) A[b] = sa4[b];          // elems 0..31

#define CIF_STEP(at, dst)                              \
  {                                                    \
    const float s_   = acc + (at);                     \
    const float au1_ = 1.0f - acc;                     \
    const float au2_ = (at) - au1_;                    \
    acc = (s_ >= 1.0f) ? au2_ : s_;                    \
    (dst) = acc;                                       \
  }

  for (int t = 0; t < T_LEN; t += 64) {
    const int q = t >> 2;
    // phase 1: prefetch elems t+32..63 into B; process A (t..t+31)
    #pragma unroll
    for (int b = 0; b < 8; ++b) B[b] = sa4[q + 8 + b];
    #pragma unroll
    for (int b = 0; b < 8; ++b) {
      const float4 v = A[b];
      float4 o;
      CIF_STEP(v.x, o.x); CIF_STEP(v.y, o.y);
      CIF_STEP(v.z, o.z); CIF_STEP(v.w, o.w);
      *(float4*)&atr[t + 4 * b] = o;
    }
    // phase 2: prefetch elems t+64..95 into A; process B (t+32..t+63)
    #pragma unroll
    for (int b = 0; b < 8; ++b) A[b] = sa4[q + 16 + b];   // pad covers t=T-64
    #pragma unroll
    for (int b = 0; b < 8; ++b) {
      const float4 v = B[b];
      float4 o;
      CIF_STEP(v.x, o.x); CIF_STEP(v.y, o.y);
      CIF_STEP(v.z, o.z); CIF_STEP(v.w, o.w);
      *(float4*)&atr[t + 32 + 4 * b] = o;
    }
  }
#undef CIF_STEP
}

// parallel fire extraction + compaction + alpha sum (4 elems/thread, 16 iters).
// fire recomputed from trace: bit-identical fp32 ops to kscan's decision.
__global__ __launch_bounds__(256) void kscan2(
    const float* __restrict__ alpha, const float* __restrict__ atr,
    int* __restrict__ fire_t, float* __restrict__ wu1, float* __restrict__ wu2,
    int* __restrict__ meta, float* __restrict__ alphas_out)
{
  __shared__ int wsum[4];
  __shared__ float fsum[4];
  const int tid = threadIdx.x;
  const int lane = tid & 63, wv = tid >> 6;
  const unsigned long long bl = (1ull << lane) - 1ull;
  int gbase = 0;
  float asum = 0.f;
  for (int it = 0; it < 16; ++it) {
    const int tb = it * 1024 + tid * 4;
    const float4 a4 = *(const float4*)&alpha[tb];
    const float4 t4 = *(const float4*)&atr[tb];
    const float prev0 = (tb == 0) ? 0.f : atr[tb - 1];
    const float pv[4] = {prev0, t4.x, t4.y, t4.z};
    const float av[4] = {a4.x, a4.y, a4.z, a4.w};
    bool f[4];
    #pragma unroll
    for (int u = 0; u < 4; ++u) {
      f[u] = (pv[u] + av[u] >= 1.0f);    // same fp32 op as kscan
      asum += av[u];
    }
    unsigned long long m[4];
    #pragma unroll
    for (int u = 0; u < 4; ++u) m[u] = __ballot(f[u]);
    if (lane == 0)
      wsum[wv] = __popcll(m[0]) + __popcll(m[1]) + __popcll(m[2]) + __popcll(m[3]);
    __syncthreads();
    int wbase = gbase, total = 0;
    #pragma unroll
    for (int w = 0; w < 4; ++w) {
      if (w < wv) wbase += wsum[w];
      total += wsum[w];
    }
    const int lanepre = __popcll(m[0] & bl) + __popcll(m[1] & bl) +
                        __popcll(m[2] & bl) + __popcll(m[3] & bl);
    int sub = 0;
    #pragma unroll
    for (int u = 0; u < 4; ++u) {
      if (f[u]) {
        const int idx = wbase + lanepre + sub;
        fire_t[idx] = tb + u;
        const float au1 = 1.0f - pv[u];
        wu1[idx] = au1;
        wu2[idx] = av[u] - au1;
        ++sub;
      }
    }
    gbase += total;
    __syncthreads();   // protect wsum reuse
  }
  #pragma unroll
  for (int m2 = 1; m2 < 64; m2 <<= 1) asum += __shfl_xor(asum, m2, 64);
  if (lane == 0) fsum[wv] = asum;
  __syncthreads();
  if (tid == 0) {
    alphas_out[0] = fsum[0] + fsum[1] + fsum[2] + fsum[3];
    meta[0] = gbase;
    meta[1] = (atr[T_LEN - 1] > 0.0f) ? 1 : 0;
  }
}

// per-output-row segmented weighted reduction over encoder rows
__global__ __launch_bounds__(256) void kscat(
    const float* __restrict__ x, const float* __restrict__ alpha,
    const int* __restrict__ fire_t, const float* __restrict__ wu1,
    const float* __restrict__ wu2, const int* __restrict__ meta,
    float* __restrict__ out)
{
  const int r = blockIdx.x;          // output row 0..T (16385 rows)
  const int tid = threadIdx.x;       // 4 floats each (H=1024)
  const int nf = meta[0];
  float4 acc = make_float4(0.f, 0.f, 0.f, 0.f);
  if (r < nf || (r == nf && meta[1])) {
    const bool isfin = (r == nf);
    const int tprev = (r > 0) ? fire_t[r - 1] : -1;
    const int tend = isfin ? (T_LEN - 1) : fire_t[r];
    const float wprev = (r > 0) ? wu2[r - 1] : 0.f;
    const float wlast = isfin ? 0.f : wu1[r];
    for (int t = (tprev < 0 ? 0 : tprev); t <= tend; ++t) {
      float w;
      if (!isfin && t == tend)      w = wlast;   // a_u1 at this row's fire
      else if (t == tprev)          w = wprev;   // a_u2 carried from prev fire
      else                          w = alpha[t];
      const float4 xv = ((const float4*)x)[(size_t)t * 256 + tid];
      acc.x = fmaf(w, xv.x, acc.x);
      acc.y = fmaf(w, xv.y, acc.y);
      acc.z = fmaf(w, xv.z, acc.z);
      acc.w = fmaf(w, xv.w, acc.w);
    }
  }
  ((float4*)out)[(size_t)r * 256 + tid] = acc;   // full overwrite (poison-safe)
}

extern "C" void kernel_launch(void* const* d_in, const int* in_sizes, int n_in,
                              void* d_out, int out_size, void* d_ws, size_t ws_size,
                              hipStream_t stream) {
  const float* enc   = (const float*)d_in[0];
  const float* convw = (const float*)d_in[1];
  const float* convb = (const float*)d_in[2];
  const float* lng   = (const float*)d_in[3];
  const float* lnb   = (const float*)d_in[4];
  const float* linw  = (const float*)d_in[5];
  const float* linb  = (const float*)d_in[6];
  float* out = (float*)d_out;

  float* ws     = (float*)d_ws;
  float* wt     = ws;                      // 786432 floats
  float* alpha  = ws + 786432;             // 16384
  int*   fire_t = (int*)(ws + 802816);     // 16384
  float* wu1    = ws + 819200;             // 16384
  float* wu2    = ws + 835584;             // 16384
  int*   meta   = (int*)(ws + 851968);     // 2
  float* atr    = ws + 851976;             // 16384 (acc trace)

  float* part = out;                       // [T][C] scratch in d_out; kscat overwrites

  hipLaunchKernelGGL(kwt,    dim3(1024),  dim3(256), 0, stream, convw, wt);
  hipLaunchKernelGGL(kconv,  dim3(512),   dim3(256), 0, stream, enc, wt, part);
  hipLaunchKernelGGL(kadd,   dim3(16384), dim3(64),  0, stream,
                     part, convb, lng, lnb, linw, linb, alpha);
  hipLaunchKernelGGL(kscan,  dim3(1),     dim3(256), 0, stream, alpha, atr);
  hipLaunchKernelGGL(kscan2, dim3(1),     dim3(256), 0, stream,
                     alpha, atr, fire_t, wu1, wu2, meta, out + (size_t)16385 * 1024);
  hipLaunchKernelGGL(kscat,  dim3(16385), dim3(256), 0, stream,
                     enc, alpha, fire_t, wu1, wu2, meta, out);
}

// Round 12
// 717.718 us; speedup vs baseline: 1.1316x; 1.1316x over previous
//
#include <hip/hip_runtime.h>
#include <math.h>

#define T_LEN 16384
#define H_DIM 1024
#define C_DIM 256
#define BKC 16

// ---------------- ws layout (float offsets) ----------------
// [0, 786432)        wt    : transposed weights (3, H, C)
// [786432, 802816)   alpha : (T)
// [802816, 819200)   fire_t (int)
// [819200, 835584)   wu1
// [835584, 851968)   wu2
// [851968, 851976)   meta: nf (int), finflag (int)
// [851976, 868360)   atr  : acc trace (T)
// conv partials [2][T][C] live in d_out[0 .. 2*T*C) — kscat overwrites last.
//
// JOURNAL r11: explicit double-buffer REGRESSED (331->417us): VGPR 68->216
// (unrolled dbuf body keeps areg/aw/bw live across phases) and the mid-compute
// A_WRITE forced vmcnt(0) which drains the B-prefetch queue too (vmcnt is
// ordered). Reverted to single-buffer; occupancy restored via split-K=2
// (grid 1024 -> 4 blocks/CU = 16 waves/CU; TLP hides the barrier drain).

// transpose conv_w (C,H,3) -> wt (3,H,C)  [coalesced writes]
__global__ __launch_bounds__(256) void kwt(const float* __restrict__ w,
                                           float* __restrict__ wt) {
  int idx = blockIdx.x * 256 + threadIdx.x;   // = h*256 + c
  int h = idx >> 8;
  int c = idx & 255;
  const float* s = w + ((size_t)c * H_DIM + h) * 3;
  float a0 = s[0], a1 = s[1], a2 = s[2];
  wt[((size_t)0 * H_DIM + h) * C_DIM + c] = a0;
  wt[((size_t)1 * H_DIM + h) * C_DIM + c] = a1;
  wt[((size_t)2 * H_DIM + h) * C_DIM + c] = a2;
}

// conv1d(K=3), 3-tap fused, 8x4 blocking, BM=64 x BN=128, split-K=2.
// grid 1024: tile = bx>>2 (64 t-rows), ch = (bx>>1)&1 (c half), kh = bx&1 (h half).
__global__ __launch_bounds__(256) void kconv(
    const float* __restrict__ x, const float* __restrict__ wt,
    float* __restrict__ part)
{
  __shared__ float As[BKC][68];      // [h_local][t_local 0..65] (66 = 64 + halo)
  __shared__ float Bs[3][BKC][128];  // [tap][h_local][c]  (24 KB)
  const int tid  = threadIdx.x;
  const int tile = blockIdx.x >> 2;
  const int ch   = (blockIdx.x >> 1) & 1;
  const int kh   = blockIdx.x & 1;
  const int t0   = tile * 64;
  const int c0   = ch * 128;
  const int i = tid >> 5;        // 0..7  row group (rows 8i..8i+7)
  const int j = tid & 31;        // 0..31 col group (cols c0+4j..+3)
  const int wv   = tid >> 6;     // wave 0..3
  const int lane = tid & 63;

  float acc[8][4];
  #pragma unroll
  for (int a0 = 0; a0 < 8; ++a0)
    #pragma unroll
    for (int b0 = 0; b0 < 4; ++b0) acc[a0][b0] = 0.f;

  const int tloc = tid >> 2;          // 0..63 A-stage row
  const int hg   = tid & 3;           // h sub-group (4 h per float4)

  for (int kt = 0; kt < 32; ++kt) {
    const int h0 = kh * 512 + kt * BKC;

    // ---- A tile: global -> reg (transposed store needs the VGPR hop) ----
    float4 areg0 = make_float4(0.f, 0.f, 0.f, 0.f), areg1 = areg0;
    {
      const int tr = t0 + tloc - 1;                       // halo: row t0-1
      if (tr >= 0 && tr < T_LEN)
        areg0 = *(const float4*)(x + (size_t)tr * H_DIM + h0 + 4 * hg);
      if (tid < 8) {                                      // rows 64,65 of the 66
        const int tl2 = 64 + (tid >> 2);
        const int tr2 = t0 + tl2 - 1;
        if (tr2 >= 0 && tr2 < T_LEN)
          areg1 = *(const float4*)(x + (size_t)tr2 * H_DIM + h0 + 4 * (tid & 3));
      }
    }
    __syncthreads();   // previous iteration's LDS readers done

    // ---- B tile: global -> LDS direct, 2 rows (1 KB) per issue, 6/wave ----
    #pragma unroll
    for (int it = 0; it < 6; ++it) {
      const int r  = 6 * wv + it;         // 0..23
      const int dl = r >> 3;              // tap 0..2
      const int kk = (r & 7) * 2;         // h_local 0,2,..,14
      const float* src = wt + ((size_t)dl * H_DIM + h0 + kk + (lane >> 5)) * C_DIM
                            + c0 + 4 * (lane & 31);
      __builtin_amdgcn_global_load_lds(
          (const __attribute__((address_space(1))) unsigned int*)src,
          (__attribute__((address_space(3))) unsigned int*)&Bs[dl][kk][0],
          16, 0, 0);
    }
    As[4 * hg + 0][tloc] = areg0.x; As[4 * hg + 1][tloc] = areg0.y;
    As[4 * hg + 2][tloc] = areg0.z; As[4 * hg + 3][tloc] = areg0.w;
    if (tid < 8) {
      const int tl2 = 64 + (tid >> 2), hg2 = (tid & 3) * 4;
      As[hg2 + 0][tl2] = areg1.x; As[hg2 + 1][tl2] = areg1.y;
      As[hg2 + 2][tl2] = areg1.z; As[hg2 + 3][tl2] = areg1.w;
    }
    __syncthreads();   // drains vmcnt (gload_lds) + lgkmcnt (ds_write)

    #pragma unroll
    for (int k = 0; k < BKC; ++k) {
      float aw[10];
      *(float4*)&aw[0] = *(const float4*)&As[k][8 * i];
      *(float4*)&aw[4] = *(const float4*)&As[k][8 * i + 4];
      *(float2*)&aw[8] = *(const float2*)&As[k][8 * i + 8];
      float bw[3][4];
      #pragma unroll
      for (int dl = 0; dl < 3; ++dl)
        *(float4*)&bw[dl][0] = *(const float4*)&Bs[dl][k][4 * j];
      // out local row r=8i+ii, tap dl uses As window index ii+dl
      #pragma unroll
      for (int ii = 0; ii < 8; ++ii)
        #pragma unroll
        for (int qq = 0; qq < 4; ++qq)
          acc[ii][qq] = fmaf(aw[ii],     bw[0][qq],
                        fmaf(aw[ii + 1], bw[1][qq],
                        fmaf(aw[ii + 2], bw[2][qq], acc[ii][qq])));
    }
  }

  float* p = part + (size_t)kh * T_LEN * C_DIM;
  #pragma unroll
  for (int ii = 0; ii < 8; ++ii) {
    const size_t t = t0 + 8 * i + ii;
    *(float4*)&p[t * C_DIM + c0 + 4 * j] =
        make_float4(acc[ii][0], acc[ii][1], acc[ii][2], acc[ii][3]);
  }
}

// combine split-K partials + bias + LN + ReLU + linear + sigmoid -> alpha[t]
// one wave per t-row. (Same combine order as round-4: (p0+p1)+cb — validated.)
__global__ __launch_bounds__(64) void kadd(
    const float* __restrict__ part, const float* __restrict__ cb,
    const float* __restrict__ lng, const float* __restrict__ lnb,
    const float* __restrict__ lw, const float* __restrict__ lb,
    float* __restrict__ alpha)
{
  const int row = blockIdx.x;
  const int l = threadIdx.x;            // 0..63, cols 4l..4l+3
  const float4 p0 = *(const float4*)&part[(size_t)row * C_DIM + 4 * l];
  const float4 p1 = *(const float4*)&part[(size_t)T_LEN * C_DIM + (size_t)row * C_DIM + 4 * l];
  const float4 cb4 = *(const float4*)&cb[4 * l];
  float v[4] = {p0.x + p1.x + cb4.x, p0.y + p1.y + cb4.y,
                p0.z + p1.z + cb4.z, p0.w + p1.w + cb4.w};
  float s = v[0] + v[1] + v[2] + v[3];
  #pragma unroll
  for (int m = 1; m < 64; m <<= 1) s += __shfl_xor(s, m, 64);
  const float mu = s * (1.0f / 256.0f);
  float ss = 0.f;
  #pragma unroll
  for (int q = 0; q < 4; ++q) { const float d = v[q] - mu; ss += d * d; }
  #pragma unroll
  for (int m = 1; m < 64; m <<= 1) ss += __shfl_xor(ss, m, 64);
  const float rstd = 1.0f / sqrtf(ss * (1.0f / 256.0f) + 1e-5f);
  const float4 g4 = *(const float4*)&lng[4 * l];
  const float4 b4 = *(const float4*)&lnb[4 * l];
  const float4 w4 = *(const float4*)&lw[4 * l];
  const float gg[4] = {g4.x, g4.y, g4.z, g4.w};
  const float bb[4] = {b4.x, b4.y, b4.z, b4.w};
  const float ww[4] = {w4.x, w4.y, w4.z, w4.w};
  float dot = 0.f;
  #pragma unroll
  for (int q = 0; q < 4; ++q) {
    float h = (v[q] - mu) * rstd * gg[q] + bb[q];
    h = fmaxf(h, 0.f);
    dot = fmaf(h, ww[q], dot);
  }
  #pragma unroll
  for (int m = 1; m < 64; m <<= 1) dot += __shfl_xor(dot, m, 64);
  if (l == 0)
    alpha[row] = 1.0f / (1.0f + expf(-(dot + lb[0])));
}

// exact-fp32 serial CIF chain. Ping-pong 32-elem buffers, padded LDS,
// 5-op exact core. Op order matches jax bit-for-bit.
__global__ __launch_bounds__(256) void kscan(const float* __restrict__ alpha,
                                             float* __restrict__ atr)
{
  __shared__ float sa[T_LEN + 64];   // 64-float pad: prefetch runs past end
  const int tid = threadIdx.x;
  #pragma unroll
  for (int b = 0; b < 16; ++b)
    ((float4*)sa)[b * 256 + tid] = ((const float4*)alpha)[b * 256 + tid];
  if (tid < 16)
    ((float4*)sa)[4096 + tid] = make_float4(0.f, 0.f, 0.f, 0.f);
  __syncthreads();
  if (tid != 0) return;

  const float4* sa4 = (const float4*)sa;
  float acc = 0.f;
  float4 A[8], B[8];
  #pragma unroll
  for (int b = 0; b < 8; ++b) A[b] = sa4[b];          // elems 0..31

#define CIF_STEP(at, dst)                              \
  {                                                    \
    const float s_   = acc + (at);                     \
    const float au1_ = 1.0f - acc;                     \
    const float au2_ = (at) - au1_;                    \
    acc = (s_ >= 1.0f) ? au2_ : s_;                    \
    (dst) = acc;                                       \
  }

  for (int t = 0; t < T_LEN; t += 64) {
    const int q = t >> 2;
    // phase 1: prefetch elems t+32..63 into B; process A (t..t+31)
    #pragma unroll
    for (int b = 0; b < 8; ++b) B[b] = sa4[q + 8 + b];
    #pragma unroll
    for (int b = 0; b < 8; ++b) {
      const float4 v = A[b];
      float4 o;
      CIF_STEP(v.x, o.x); CIF_STEP(v.y, o.y);
      CIF_STEP(v.z, o.z); CIF_STEP(v.w, o.w);
      *(float4*)&atr[t + 4 * b] = o;
    }
    // phase 2: prefetch elems t+64..95 into A; process B (t+32..t+63)
    #pragma unroll
    for (int b = 0; b < 8; ++b) A[b] = sa4[q + 16 + b];   // pad covers t=T-64
    #pragma unroll
    for (int b = 0; b < 8; ++b) {
      const float4 v = B[b];
      float4 o;
      CIF_STEP(v.x, o.x); CIF_STEP(v.y, o.y);
      CIF_STEP(v.z, o.z); CIF_STEP(v.w, o.w);
      *(float4*)&atr[t + 32 + 4 * b] = o;
    }
  }
#undef CIF_STEP
}

// parallel fire extraction + compaction + alpha sum (4 elems/thread, 16 iters).
// fire recomputed from trace: bit-identical fp32 ops to kscan's decision.
__global__ __launch_bounds__(256) void kscan2(
    const float* __restrict__ alpha, const float* __restrict__ atr,
    int* __restrict__ fire_t, float* __restrict__ wu1, float* __restrict__ wu2,
    int* __restrict__ meta, float* __restrict__ alphas_out)
{
  __shared__ int wsum[4];
  __shared__ float fsum[4];
  const int tid = threadIdx.x;
  const int lane = tid & 63, wv = tid >> 6;
  const unsigned long long bl = (1ull << lane) - 1ull;
  int gbase = 0;
  float asum = 0.f;
  for (int it = 0; it < 16; ++it) {
    const int tb = it * 1024 + tid * 4;
    const float4 a4 = *(const float4*)&alpha[tb];
    const float4 t4 = *(const float4*)&atr[tb];
    const float prev0 = (tb == 0) ? 0.f : atr[tb - 1];
    const float pv[4] = {prev0, t4.x, t4.y, t4.z};
    const float av[4] = {a4.x, a4.y, a4.z, a4.w};
    bool f[4];
    #pragma unroll
    for (int u = 0; u < 4; ++u) {
      f[u] = (pv[u] + av[u] >= 1.0f);    // same fp32 op as kscan
      asum += av[u];
    }
    unsigned long long m[4];
    #pragma unroll
    for (int u = 0; u < 4; ++u) m[u] = __ballot(f[u]);
    if (lane == 0)
      wsum[wv] = __popcll(m[0]) + __popcll(m[1]) + __popcll(m[2]) + __popcll(m[3]);
    __syncthreads();
    int wbase = gbase, total = 0;
    #pragma unroll
    for (int w = 0; w < 4; ++w) {
      if (w < wv) wbase += wsum[w];
      total += wsum[w];
    }
    const int lanepre = __popcll(m[0] & bl) + __popcll(m[1] & bl) +
                        __popcll(m[2] & bl) + __popcll(m[3] & bl);
    int sub = 0;
    #pragma unroll
    for (int u = 0; u < 4; ++u) {
      if (f[u]) {
        const int idx = wbase + lanepre + sub;
        fire_t[idx] = tb + u;
        const float au1 = 1.0f - pv[u];
        wu1[idx] = au1;
        wu2[idx] = av[u] - au1;
        ++sub;
      }
    }
    gbase += total;
    __syncthreads();   // protect wsum reuse
  }
  #pragma unroll
  for (int m2 = 1; m2 < 64; m2 <<= 1) asum += __shfl_xor(asum, m2, 64);
  if (lane == 0) fsum[wv] = asum;
  __syncthreads();
  if (tid == 0) {
    alphas_out[0] = fsum[0] + fsum[1] + fsum[2] + fsum[3];
    meta[0] = gbase;
    meta[1] = (atr[T_LEN - 1] > 0.0f) ? 1 : 0;
  }
}

// per-output-row segmented weighted reduction over encoder rows
__global__ __launch_bounds__(256) void kscat(
    const float* __restrict__ x, const float* __restrict__ alpha,
    const int* __restrict__ fire_t, const float* __restrict__ wu1,
    const float* __restrict__ wu2, const int* __restrict__ meta,
    float* __restrict__ out)
{
  const int r = blockIdx.x;          // output row 0..T (16385 rows)
  const int tid = threadIdx.x;       // 4 floats each (H=1024)
  const int nf = meta[0];
  float4 acc = make_float4(0.f, 0.f, 0.f, 0.f);
  if (r < nf || (r == nf && meta[1])) {
    const bool isfin = (r == nf);
    const int tprev = (r > 0) ? fire_t[r - 1] : -1;
    const int tend = isfin ? (T_LEN - 1) : fire_t[r];
    const float wprev = (r > 0) ? wu2[r - 1] : 0.f;
    const float wlast = isfin ? 0.f : wu1[r];
    for (int t = (tprev < 0 ? 0 : tprev); t <= tend; ++t) {
      float w;
      if (!isfin && t == tend)      w = wlast;   // a_u1 at this row's fire
      else if (t == tprev)          w = wprev;   // a_u2 carried from prev fire
      else                          w = alpha[t];
      const float4 xv = ((const float4*)x)[(size_t)t * 256 + tid];
      acc.x = fmaf(w, xv.x, acc.x);
      acc.y = fmaf(w, xv.y, acc.y);
      acc.z = fmaf(w, xv.z, acc.z);
      acc.w = fmaf(w, xv.w, acc.w);
    }
  }
  ((float4*)out)[(size_t)r * 256 + tid] = acc;   // full overwrite (poison-safe)
}

extern "C" void kernel_launch(void* const* d_in, const int* in_sizes, int n_in,
                              void* d_out, int out_size, void* d_ws, size_t ws_size,
                              hipStream_t stream) {
  const float* enc   = (const float*)d_in[0];
  const float* convw = (const float*)d_in[1];
  const float* convb = (const float*)d_in[2];
  const float* lng   = (const float*)d_in[3];
  const float* lnb   = (const float*)d_in[4];
  const float* linw  = (const float*)d_in[5];
  const float* linb  = (const float*)d_in[6];
  float* out = (float*)d_out;

  float* ws     = (float*)d_ws;
  float* wt     = ws;                      // 786432 floats
  float* alpha  = ws + 786432;             // 16384
  int*   fire_t = (int*)(ws + 802816);     // 16384
  float* wu1    = ws + 819200;             // 16384
  float* wu2    = ws + 835584;             // 16384
  int*   meta   = (int*)(ws + 851968);     // 2
  float* atr    = ws + 851976;             // 16384 (acc trace)

  float* part = out;                       // [2][T][C] scratch in d_out; kscat overwrites

  hipLaunchKernelGGL(kwt,    dim3(1024),  dim3(256), 0, stream, convw, wt);
  hipLaunchKernelGGL(kconv,  dim3(1024),  dim3(256), 0, stream, enc, wt, part);
  hipLaunchKernelGGL(kadd,   dim3(16384), dim3(64),  0, stream,
                     part, convb, lng, lnb, linw, linb, alpha);
  hipLaunchKernelGGL(kscan,  dim3(1),     dim3(256), 0, stream, alpha, atr);
  hipLaunchKernelGGL(kscan2, dim3(1),     dim3(256), 0, stream,
                     alpha, atr, fire_t, wu1, wu2, meta, out + (size_t)16385 * 1024);
  hipLaunchKernelGGL(kscat,  dim3(16385), dim3(256), 0, stream,
                     enc, alpha, fire_t, wu1, wu2, meta, out);
}